// Round 6
// baseline (317.014 us; speedup 1.0000x reference)
//
#include <hip/hip_runtime.h>
#include <cstdint>
#include <cstddef>

typedef unsigned short ushort_t;
typedef __attribute__((ext_vector_type(8))) short bf16x8;
typedef __attribute__((ext_vector_type(4))) float f32x4;

#define MROWS 16384
#define KDIM  1024
#define NDIM  2048
#define HDIM  512
#define NTILE 16            // K tiles of 64

static __device__ __forceinline__ unsigned short f2bf(float f) {
    unsigned int u = __float_as_uint(f);
    u += 0x7fffu + ((u >> 16) & 1u);   // round-to-nearest-even
    return (unsigned short)(u >> 16);
}

static __device__ __forceinline__ float sigmoid_f(float x) {
    return 1.0f / (1.0f + __expf(-x));
}
static __device__ __forceinline__ float tanh_f(float x) {
    float t = __expf(2.0f * x);
    return 1.0f - 2.0f / (t + 1.0f);   // saturates cleanly at +/-1 for large |x|
}

// ---------------------------------------------------------------------------
// Pass 0 (W only now): Bt via LDS transpose, 512 blocks.
//   Bt[n'][k] = bf16(Wcat[k][col]), n' = 4h+g, col = g*512+h
// The A-pack pass is GONE: gemm_cell reg-stages A from fp32 x/h_prev directly.
// ---------------------------------------------------------------------------
__global__ __launch_bounds__(256) void pack_bt(const float* __restrict__ Wi,
                                               const float* __restrict__ Wh,
                                               ushort_t* __restrict__ Bt) {
    __shared__ ushort_t sm[64][72];                 // transpose tile (+8 pad)
    const int tid = threadIdx.x;
    int b2 = blockIdx.x;                            // 0..511
    int kt = b2 >> 5;                               // k-tile 0..15 (64 rows each)
    int ct = b2 & 31;                               // col-tile 0..31 (64 cols each)
    const float* W = (kt < 8) ? (Wi + (size_t)(kt * 64) * NDIM)
                              : (Wh + (size_t)((kt - 8) * 64) * NDIM);
    // coalesced 64x64 fp32 tile load -> bf16 LDS
    int c0 = (tid & 15) * 4;
    int r0 = tid >> 4;                              // 0..15
#pragma unroll
    for (int r = 0; r < 4; ++r) {
        int krow = r * 16 + r0;
        float4 v = *((const float4*)(W + (size_t)krow * NDIM + ct * 64 + c0));
        sm[krow][c0 + 0] = f2bf(v.x);
        sm[krow][c0 + 1] = f2bf(v.y);
        sm[krow][c0 + 2] = f2bf(v.z);
        sm[krow][c0 + 3] = f2bf(v.w);
    }
    __syncthreads();
    int g = (ct * 64) >> 9;                         // gate 0..3 (tile never spans g)
    int h0 = ct * 64 - g * 512;
#pragma unroll
    for (int q = tid; q < 512; q += 256) {
        int cc = q >> 3;                            // col within tile
        int kc = (q & 7) * 8;                       // k chunk within tile
        ushort_t o[8] __attribute__((aligned(16)));
#pragma unroll
        for (int j = 0; j < 8; ++j) o[j] = sm[kc + j][cc];
        int np = 4 * (h0 + cc) + g;
        *((uint4*)(Bt + (size_t)np * KDIM + kt * 64 + kc)) = *((const uint4*)o);
    }
}

// ---------------------------------------------------------------------------
// Pass 1: 256x256-tile bf16 MFMA GEMM, A reg-staged from fp32 x/h_prev with
// in-register v_cvt_pk_bf16_f32 and swizzled ds_write_b128 (pack fused in).
// B staged via global_load_lds from Bt (pre-swizzled source) as before.
//
// Per tile t (buf p = t&1), 4 phases m0n0 -> m0n1 -> m1n0 -> m1n1:
//   top: issue 8x float4 A(t+2) reg loads (registers: no LDS hazard)
//   P1: ds_read af0-3 + b0v; MFMA m0n0;  B1 (plain barrier)
//   P2: ds_read b1v;         MFMA m0n1;  B2; issue 4x B(t+2) global_load_lds
//   P3: ds_read af4-7;       MFMA m1n0;
//       B3 = s_waitcnt vmcnt(4) lgkmcnt(0) + s_barrier
//       then cvt_pk + 4x ds_write_b128 A(t+2) into buf p (region just freed)
//   P4: MFMA m1n1 (regs only); B4 (plain barrier)
//
// vmcnt(4) at B3: issue order is [...A-regs(t+2) x8][Bg(t+2) x4], so 4
// leaves exactly Bg(t+2) in flight and drains A-regs(t+2) AND Bg(t+1)
// (older) -> barrier publishes t+1's B and (written at t-1) t+1's A.
// WAR: A-region reads all retired by B3's lgkmcnt(0); B-region reads all
// consumed before B2. Never vmcnt(0) in steady state. Barrier count is
// wave-uniform (both branches of each conditional contain one s_barrier).
// ---------------------------------------------------------------------------
__global__ __launch_bounds__(512, 2) void gemm_cell(const float* __restrict__ xg,
                                                    const float* __restrict__ hg,
                                                    const ushort_t* __restrict__ Bt,
                                                    const float* __restrict__ b,
                                                    const float* __restrict__ c_prev,
                                                    float* __restrict__ h_out,
                                                    float* __restrict__ c_out) {
    __shared__ ushort_t lds[2][32768];             // 128 KB: per buf A 32KB + B 32KB

    const int tid  = threadIdx.x;
    const int w    = tid >> 6;
    const int lane = tid & 63;
    const int mi   = w >> 2;                       // 0..1  (M wave row)
    const int nj   = w & 3;                        // 0..3  (N wave col)
    // XCD-aware swizzle: 512 blocks, 512%8==0 -> bijective
    int bid = blockIdx.x;
    int lid = (bid & 7) * 64 + (bid >> 3);
    const int m0 = (lid >> 3) * 256;               // 64 m-tiles
    const int n0 = (lid & 7) * 256;                // 8 n-tiles (permuted N)
    const int lr   = lane & 15;
    const int quad = lane >> 4;
    const int sw   = lr & 7;                       // read-side swizzle key

    // A reg-staging constants: thread owns row arow (0..255), k-half `half`
    // (32 fp32 = 128 B contiguous). bf16 write slot = chunk ^ (row&7) -- same
    // mapping the af reads expect (slot s at row r holds global chunk s^(r&7)).
    const int arow = tid >> 1;
    const int half = tid & 1;
    const int awk  = arow & 7;

    // B staging constants (unchanged): LDS slot (row, ch) <- global chunk
    // (ch ^ (row&7)) via pre-swizzled global source.
    const int trow0 = tid >> 3;
    const int chg   = (tid & 7) ^ (trow0 & 7);
    const size_t b_base = (size_t)(n0 + trow0) * KDIM + chg * 8;
    const int    l_base = tid * 16;                // byte offset, lane-linear x16

#define STAGE_B_SLOT(kt, bufi, r_)                                              \
    __builtin_amdgcn_global_load_lds(                                           \
        (const __attribute__((address_space(1))) void*)(Bt + b_base +           \
            (size_t)(kt) * 64 + (size_t)(r_) * 64 * KDIM),                      \
        (__attribute__((address_space(3))) void*)((char*)&lds[bufi][16384] +    \
            l_base + (r_) * 8192), 16, 0, 0)

#define ALOAD(arv, kt2) do {                                                    \
    const float* ab_ = ((kt2) < 8)                                              \
        ? (xg + (size_t)(m0 + arow) * 512 + (kt2) * 64 + half * 32)             \
        : (hg + (size_t)(m0 + arow) * 512 + ((kt2) - 8) * 64 + half * 32);      \
    _Pragma("unroll")                                                           \
    for (int i_ = 0; i_ < 8; ++i_) arv[i_] = ((const float4*)ab_)[i_];          \
} while (0)

#define CVTW(arv, bufi) do {                                                    \
    ushort_t* Aw_ = &lds[bufi][0];                                              \
    _Pragma("unroll")                                                           \
    for (int j_ = 0; j_ < 4; ++j_) {                                            \
        uint4 pk_;                                                              \
        asm("v_cvt_pk_bf16_f32 %0, %1, %2" : "=v"(pk_.x)                        \
            : "v"(arv[2 * j_].x), "v"(arv[2 * j_].y));                          \
        asm("v_cvt_pk_bf16_f32 %0, %1, %2" : "=v"(pk_.y)                        \
            : "v"(arv[2 * j_].z), "v"(arv[2 * j_].w));                          \
        asm("v_cvt_pk_bf16_f32 %0, %1, %2" : "=v"(pk_.z)                        \
            : "v"(arv[2 * j_ + 1].x), "v"(arv[2 * j_ + 1].y));                  \
        asm("v_cvt_pk_bf16_f32 %0, %1, %2" : "=v"(pk_.w)                        \
            : "v"(arv[2 * j_ + 1].z), "v"(arv[2 * j_ + 1].w));                  \
        *((uint4*)(Aw_ + (size_t)(arow * 8 + ((half * 4 + j_) ^ awk)) * 8)) = pk_; \
    }                                                                           \
} while (0)

    f32x4 acc[8][4];
#pragma unroll
    for (int i = 0; i < 8; ++i)
#pragma unroll
        for (int j = 0; j < 4; ++j) acc[i][j] = (f32x4){0.f, 0.f, 0.f, 0.f};

    // ---- prologue: A(0),A(1) via regs; B(0),B(1) via gload_lds ----
    // issue order enforced by empty asm memory fences (vmcnt counting).
    {
        float4 ar0v[8], ar1v[8];
        ALOAD(ar0v, 0);                            // kt=0 (<8 -> x)
        asm volatile("" ::: "memory");
        STAGE_B_SLOT(0, 0, 0); STAGE_B_SLOT(0, 0, 1);
        STAGE_B_SLOT(0, 0, 2); STAGE_B_SLOT(0, 0, 3);
        asm volatile("" ::: "memory");
        ALOAD(ar1v, 1);                            // kt=1 (<8 -> x)
        asm volatile("" ::: "memory");
        STAGE_B_SLOT(1, 1, 0); STAGE_B_SLOT(1, 1, 1);
        STAGE_B_SLOT(1, 1, 2); STAGE_B_SLOT(1, 1, 3);
        asm volatile("s_waitcnt vmcnt(16)" ::: "memory");   // A(0) regs landed
        CVTW(ar0v, 0);
        asm volatile("s_waitcnt vmcnt(4)" ::: "memory");    // A(1) regs + B(0) landed
        CVTW(ar1v, 1);
        // publish A(0),A(1),B(0); B(1)'s 4 loads stay in flight
        asm volatile("s_waitcnt lgkmcnt(0)\n\ts_barrier" ::: "memory");
    }

#define TILE(t_, BUF_) do {                                                         \
    const ushort_t* Ab_ = &lds[BUF_][0];                                            \
    const ushort_t* Bb_ = &lds[BUF_][16384];                                        \
    bf16x8 af[4][2], b0v[2][2], b1v[2][2];                                          \
    float4 arS[8];                                                                  \
    const bool pf_ = (t_) < NTILE - 2;                                              \
    if (pf_) ALOAD(arS, (t_) + 2);          /* regs only: no LDS hazard */          \
    /* ---- P1: read af0-3 (both k-halves) + b0v | MFMA m0n0 ---- */                \
    _Pragma("unroll")                                                               \
    for (int t2 = 0; t2 < 4; ++t2) {                                                \
        int ra = mi * 128 + t2 * 16 + lr;                                           \
        af[t2][0] = *((const bf16x8*)(Ab_ + (ra * 8 + (quad ^ sw)) * 8));           \
        af[t2][1] = *((const bf16x8*)(Ab_ + (ra * 8 + ((4 + quad) ^ sw)) * 8));     \
    }                                                                               \
    _Pragma("unroll")                                                               \
    for (int j = 0; j < 2; ++j) {                                                   \
        int rb = nj * 64 + j * 16 + lr;                                             \
        b0v[j][0] = *((const bf16x8*)(Bb_ + (rb * 8 + (quad ^ sw)) * 8));           \
        b0v[j][1] = *((const bf16x8*)(Bb_ + (rb * 8 + ((4 + quad) ^ sw)) * 8));     \
    }                                                                               \
    __builtin_amdgcn_s_setprio(1);                                                  \
    _Pragma("unroll")                                                               \
    for (int t2 = 0; t2 < 4; ++t2)                                                  \
        _Pragma("unroll")                                                           \
        for (int j = 0; j < 2; ++j) {                                               \
            acc[t2][j] = __builtin_amdgcn_mfma_f32_16x16x32_bf16(                   \
                af[t2][0], b0v[j][0], acc[t2][j], 0, 0, 0);                         \
            acc[t2][j] = __builtin_amdgcn_mfma_f32_16x16x32_bf16(                   \
                af[t2][1], b0v[j][1], acc[t2][j], 0, 0, 0);                         \
        }                                                                           \
    __builtin_amdgcn_s_setprio(0);                                                  \
    asm volatile("s_barrier" ::: "memory");       /* B1 */                          \
    /* ---- P2: read b1v | MFMA m0n1 ---- */                                        \
    _Pragma("unroll")                                                               \
    for (int j = 0; j < 2; ++j) {                                                   \
        int rb = nj * 64 + (j + 2) * 16 + lr;                                       \
        b1v[j][0] = *((const bf16x8*)(Bb_ + (rb * 8 + (quad ^ sw)) * 8));           \
        b1v[j][1] = *((const bf16x8*)(Bb_ + (rb * 8 + ((4 + quad) ^ sw)) * 8));     \
    }                                                                               \
    __builtin_amdgcn_s_setprio(1);                                                  \
    _Pragma("unroll")                                                               \
    for (int t2 = 0; t2 < 4; ++t2)                                                  \
        _Pragma("unroll")                                                           \
        for (int j = 0; j < 2; ++j) {                                               \
            acc[t2][j + 2] = __builtin_amdgcn_mfma_f32_16x16x32_bf16(               \
                af[t2][0], b1v[j][0], acc[t2][j + 2], 0, 0, 0);                     \
            acc[t2][j + 2] = __builtin_amdgcn_mfma_f32_16x16x32_bf16(               \
                af[t2][1], b1v[j][1], acc[t2][j + 2], 0, 0, 0);                     \
        }                                                                           \
    __builtin_amdgcn_s_setprio(0);                                                  \
    asm volatile("s_barrier" ::: "memory");       /* B2: all B reads retired */     \
    if (pf_) { STAGE_B_SLOT((t_) + 2, BUF_, 0); STAGE_B_SLOT((t_) + 2, BUF_, 1);    \
               STAGE_B_SLOT((t_) + 2, BUF_, 2); STAGE_B_SLOT((t_) + 2, BUF_, 3); }  \
    /* ---- P3: read af4-7 (reuse af regs) | MFMA m1n0 (b0v dies here) ---- */      \
    _Pragma("unroll")                                                               \
    for (int t2 = 0; t2 < 4; ++t2) {                                                \
        int ra = mi * 128 + (t2 + 4) * 16 + lr;                                     \
        af[t2][0] = *((const bf16x8*)(Ab_ + (ra * 8 + (quad ^ sw)) * 8));           \
        af[t2][1] = *((const bf16x8*)(Ab_ + (ra * 8 + ((4 + quad) ^ sw)) * 8));     \
    }                                                                               \
    __builtin_amdgcn_s_setprio(1);                                                  \
    _Pragma("unroll")                                                               \
    for (int t2 = 0; t2 < 4; ++t2)                                                  \
        _Pragma("unroll")                                                           \
        for (int j = 0; j < 2; ++j) {                                               \
            acc[t2 + 4][j] = __builtin_amdgcn_mfma_f32_16x16x32_bf16(               \
                af[t2][0], b0v[j][0], acc[t2 + 4][j], 0, 0, 0);                     \
            acc[t2 + 4][j] = __builtin_amdgcn_mfma_f32_16x16x32_bf16(               \
                af[t2][1], b0v[j][1], acc[t2 + 4][j], 0, 0, 0);                     \
        }                                                                           \
    __builtin_amdgcn_s_setprio(0);                                                  \
    /* B3: drain own A-reads (lgkm) + A-regs/B(t+1) (vmcnt), publish */             \
    if (pf_) {                                                                      \
        asm volatile("s_waitcnt vmcnt(4) lgkmcnt(0)\n\ts_barrier" ::: "memory");    \
        CVTW(arS, BUF_);                           /* A(t+2) -> freed region */     \
    } else {                                                                        \
        asm volatile("s_waitcnt vmcnt(0) lgkmcnt(0)\n\ts_barrier" ::: "memory");    \
    }                                                                               \
    /* ---- P4: MFMA m1n1 (registers only; covers write latency) ---- */            \
    __builtin_amdgcn_s_setprio(1);                                                  \
    _Pragma("unroll")                                                               \
    for (int t2 = 0; t2 < 4; ++t2)                                                  \
        _Pragma("unroll")                                                           \
        for (int j = 0; j < 2; ++j) {                                               \
            acc[t2 + 4][j + 2] = __builtin_amdgcn_mfma_f32_16x16x32_bf16(           \
                af[t2][0], b1v[j][0], acc[t2 + 4][j + 2], 0, 0, 0);                 \
            acc[t2 + 4][j + 2] = __builtin_amdgcn_mfma_f32_16x16x32_bf16(           \
                af[t2][1], b1v[j][1], acc[t2 + 4][j + 2], 0, 0, 0);                 \
        }                                                                           \
    __builtin_amdgcn_s_setprio(0);                                                  \
    if ((t_) == NTILE - 1) {                                                        \
        asm volatile("s_waitcnt lgkmcnt(0)\n\ts_barrier" ::: "memory");             \
    } else {                                                                        \
        asm volatile("s_barrier" ::: "memory");   /* B4 */                          \
    }                                                                               \
} while (0)

    for (int tp = 0; tp < NTILE / 2; ++tp) {
        TILE(2 * tp, 0);
        TILE(2 * tp + 1, 1);
    }
#undef TILE
#undef STAGE_B_SLOT
#undef ALOAD
#undef CVTW

    // ---- barrier-free epilogue: per-wave private 4 KB scratch in buf0 ----
    float* scr = (float*)&lds[0][0] + w * 1024;    // 16 rows x 64 cols
    const int rr = lane >> 2;                      // row within chunk
    const int hg0 = ((n0 + nj * 64) >> 2) + (lane & 3) * 4;  // 4 consecutive h
    const float4 bi4 = *((const float4*)(b + hg0));
    const float4 bff = *((const float4*)(b + 512 + hg0));
    const float4 bgg = *((const float4*)(b + 1024 + hg0));
    const float4 boo = *((const float4*)(b + 1536 + hg0));
    const float bi[4] = {bi4.x, bi4.y, bi4.z, bi4.w};
    const float bfv[4] = {bff.x, bff.y, bff.z, bff.w};
    const float bg[4] = {bgg.x, bgg.y, bgg.z, bgg.w};
    const float bo[4] = {boo.x, boo.y, boo.z, boo.w};

#pragma unroll
    for (int tm = 0; tm < 8; ++tm) {
        // write 16x64 chunk, XOR-swizzled 16B col-blocks
#pragma unroll
        for (int tn = 0; tn < 4; ++tn) {
            int c = tn * 16 + lr;
#pragma unroll
            for (int rg = 0; rg < 4; ++rg) {
                int r = quad * 4 + rg;
                int blk = (c >> 2) ^ r;            // 0..15
                scr[r * 64 + blk * 4 + (c & 3)] = acc[tm][tn][rg];
            }
        }
        // same-wave in-order DS pipe: no barrier needed
        float4 gv[4];
#pragma unroll
        for (int j = 0; j < 4; ++j) {
            int cb = (lane & 3) * 4 + j;
            gv[j] = *((const float4*)(scr + rr * 64 + (cb ^ rr) * 4));
        }
        int grow = m0 + mi * 128 + tm * 16 + rr;
        float4 cp4 = *((const float4*)(c_prev + (size_t)grow * HDIM + hg0));
        const float cpv[4] = {cp4.x, cp4.y, cp4.z, cp4.w};
        float cn[4], hv[4];
#pragma unroll
        for (int j = 0; j < 4; ++j) {
            float iv = sigmoid_f(gv[j].x + bi[j]);
            float fv = sigmoid_f(gv[j].y + bfv[j]);
            float g2 = tanh_f(gv[j].z + bg[j]);
            float ov = sigmoid_f(gv[j].w + bo[j]);
            cn[j] = fv * cpv[j] + iv * g2;
            hv[j] = ov * tanh_f(cn[j]);
        }
        float4 cno = {cn[0], cn[1], cn[2], cn[3]};
        float4 hvo = {hv[0], hv[1], hv[2], hv[3]};
        *((float4*)(c_out + (size_t)grow * HDIM + hg0)) = cno;
        *((float4*)(h_out + (size_t)grow * HDIM + hg0)) = hvo;
    }
}

// ---------------------------------------------------------------------------
// Pass 2: in-place row-wise LayerNorm on h. 2048 blocks; each wave handles
// TWO independent rows (r, r+8192) with interleaved loads/reductions (2x ILP).
// ---------------------------------------------------------------------------
__global__ __launch_bounds__(256) void ln_kernel(float* __restrict__ h,
                                                 const float* __restrict__ lw,
                                                 const float* __restrict__ lb) {
    int w = threadIdx.x >> 6;
    int lane = threadIdx.x & 63;
    int r0 = blockIdx.x * 4 + w;                   // 0..8191
    int r1 = r0 + (MROWS >> 1);                    // 8192..16383
    float* p0 = h + (size_t)r0 * HDIM + lane * 8;
    float* p1 = h + (size_t)r1 * HDIM + lane * 8;
    float4 a0 = ((const float4*)p0)[0];
    float4 c0 = ((const float4*)p0)[1];
    float4 a1 = ((const float4*)p1)[0];
    float4 c1 = ((const float4*)p1)[1];
    const float* wp = lw + lane * 8;
    const float* bp = lb + lane * 8;
    float4 w0 = ((const float4*)wp)[0];
    float4 w1 = ((const float4*)wp)[1];
    float4 b0 = ((const float4*)bp)[0];
    float4 b1 = ((const float4*)bp)[1];

    float s0  = a0.x + a0.y + a0.z + a0.w + c0.x + c0.y + c0.z + c0.w;
    float ss0 = a0.x * a0.x + a0.y * a0.y + a0.z * a0.z + a0.w * a0.w +
                c0.x * c0.x + c0.y * c0.y + c0.z * c0.z + c0.w * c0.w;
    float s1  = a1.x + a1.y + a1.z + a1.w + c1.x + c1.y + c1.z + c1.w;
    float ss1 = a1.x * a1.x + a1.y * a1.y + a1.z * a1.z + a1.w * a1.w +
                c1.x * c1.x + c1.y * c1.y + c1.z * c1.z + c1.w * c1.w;
#pragma unroll
    for (int off = 32; off > 0; off >>= 1) {
        s0  += __shfl_xor(s0, off);
        ss0 += __shfl_xor(ss0, off);
        s1  += __shfl_xor(s1, off);
        ss1 += __shfl_xor(ss1, off);
    }
    float mu0 = s0 * (1.0f / 512.0f);
    float var0 = ss0 * (1.0f / 512.0f) - mu0 * mu0;
    float rstd0 = rsqrtf(var0 + 1e-5f);
    float mu1 = s1 * (1.0f / 512.0f);
    float var1 = ss1 * (1.0f / 512.0f) - mu1 * mu1;
    float rstd1 = rsqrtf(var1 + 1e-5f);

    a0.x = (a0.x - mu0) * rstd0 * w0.x + b0.x;
    a0.y = (a0.y - mu0) * rstd0 * w0.y + b0.y;
    a0.z = (a0.z - mu0) * rstd0 * w0.z + b0.z;
    a0.w = (a0.w - mu0) * rstd0 * w0.w + b0.w;
    c0.x = (c0.x - mu0) * rstd0 * w1.x + b1.x;
    c0.y = (c0.y - mu0) * rstd0 * w1.y + b1.y;
    c0.z = (c0.z - mu0) * rstd0 * w1.z + b1.z;
    c0.w = (c0.w - mu0) * rstd0 * w1.w + b1.w;
    a1.x = (a1.x - mu1) * rstd1 * w0.x + b0.x;
    a1.y = (a1.y - mu1) * rstd1 * w0.y + b0.y;
    a1.z = (a1.z - mu1) * rstd1 * w0.z + b0.z;
    a1.w = (a1.w - mu1) * rstd1 * w0.w + b0.w;
    c1.x = (c1.x - mu1) * rstd1 * w1.x + b1.x;
    c1.y = (c1.y - mu1) * rstd1 * w1.y + b1.y;
    c1.z = (c1.z - mu1) * rstd1 * w1.z + b1.z;
    c1.w = (c1.w - mu1) * rstd1 * w1.w + b1.w;
    ((float4*)p0)[0] = a0;
    ((float4*)p0)[1] = c0;
    ((float4*)p1)[0] = a1;
    ((float4*)p1)[1] = c1;
}

extern "C" void kernel_launch(void* const* d_in, const int* in_sizes, int n_in,
                              void* d_out, int out_size, void* d_ws, size_t ws_size,
                              hipStream_t stream) {
    const float* x      = (const float*)d_in[0];
    const float* h_prev = (const float*)d_in[1];
    const float* c_prev = (const float*)d_in[2];
    const float* W_i    = (const float*)d_in[3];
    const float* W_h    = (const float*)d_in[4];
    const float* b      = (const float*)d_in[5];
    const float* ln_w   = (const float*)d_in[6];
    const float* ln_b   = (const float*)d_in[7];

    float* h_out = (float*)d_out;                       // [16384][512]
    float* c_out = h_out + (size_t)MROWS * HDIM;        // [16384][512]

    ushort_t* Bt = (ushort_t*)d_ws;                     // 4 MB

    pack_bt<<<512, 256, 0, stream>>>(W_i, W_h, Bt);
    gemm_cell<<<512, 512, 0, stream>>>(x, h_prev, Bt, b, c_prev, h_out, c_out);
    ln_kernel<<<MROWS / 8, 256, 0, stream>>>(h_out, ln_w, ln_b);
}